// Round 6
// baseline (159.594 us; speedup 1.0000x reference)
//
#include <hip/hip_runtime.h>
#include <math.h>

typedef unsigned short ushort_t;
typedef __attribute__((ext_vector_type(8))) short short8;
typedef __attribute__((ext_vector_type(4))) float f32x4;

// pack two f32 -> two bf16 (RNE) in one u32: D[15:0]=cvt(lo), D[31:16]=cvt(hi)
__device__ inline unsigned bfpair(float lo, float hi) {
  unsigned r;
  asm("v_cvt_pk_bf16_f32 %0, %1, %2" : "=v"(r) : "v"(lo), "v"(hi));
  return r;
}
// CDNA4 cross-half swaps (full-rate VALU):
__device__ inline void permswap32(unsigned &a, unsigned &b) {
  asm("v_permlane32_swap_b32 %0, %1" : "+v"(a), "+v"(b));
}
__device__ inline void permswap16(unsigned &a, unsigned &b) {
  asm("v_permlane16_swap_b32 %0, %1" : "+v"(a), "+v"(b));
}

// ---------------- transpose + convert: W[K][N] f32 -> Wt[N][K] bf16 ----------------
__global__ __launch_bounds__(256) void transpose_bf16_k(
    const float* __restrict__ W, ushort_t* __restrict__ Wt, int K, int N)
{
  __shared__ float Ls[32][33];
  const int t = threadIdx.x;
  const int n0 = blockIdx.x * 32, k0 = blockIdx.y * 32;
  const int tx = t & 31, tyb = t >> 5;
  #pragma unroll
  for (int s = 0; s < 4; ++s) {
    const int k = tyb + s * 8;
    Ls[k][tx] = W[(size_t)(k0 + k) * N + n0 + tx];
  }
  __syncthreads();
  #pragma unroll
  for (int s = 0; s < 2; ++s) {
    const int idx = t + 256 * s;
    const int n = idx >> 4, kk = (idx & 15) * 2;
    const unsigned pk = bfpair(Ls[kk][n], Ls[kk + 1][n]);
    *(unsigned*)&Wt[(size_t)(n0 + n) * K + k0 + kk] = pk;
  }
}

// ---------------- bf16 MFMA GEMM + bias + relu ----------------
// Waves inside one block cover ALL of N: wave w owns cols [w*NT*16, ...).
// Hard-coded fragment maps (HW-verified rounds 3-5):
//   A-frag lane(g,ln): A[m=ln][k=8g+i]; B-frag: B[k=8g+i][n=ln]
//   D lane(g,ln) reg r: (row=4g+r, col=ln)
template<int BS, int MT, int NT, bool A_FP32, bool OUT_BF16>
__global__ __launch_bounds__(BS) void gemm_mfma(
    const void* __restrict__ Ap, const ushort_t* __restrict__ Wt,
    const float* __restrict__ bias, void* __restrict__ Cp, int K, int N)
{
  const int wave = threadIdx.x >> 6, lane = threadIdx.x & 63;
  const int ln = lane & 15, g = lane >> 4;
  const int bm0 = blockIdx.x * (MT * 16);
  const int n0 = wave * (NT * 16);
  const f32x4 zero4 = {0.f, 0.f, 0.f, 0.f};

  f32x4 acc[MT][NT];
  #pragma unroll
  for (int mt = 0; mt < MT; ++mt)
    #pragma unroll
    for (int nt = 0; nt < NT; ++nt) acc[mt][nt] = zero4;

  const float* Af = (const float*)Ap;
  const ushort_t* Ab = (const ushort_t*)Ap;

  for (int k0 = 0; k0 < K; k0 += 32) {
    short8 af[MT];
    #pragma unroll
    for (int mt = 0; mt < MT; ++mt) {
      const size_t base = (size_t)(bm0 + mt * 16 + ln) * K + k0 + g * 8;
      if (A_FP32) {
        const float4 f0 = *(const float4*)&Af[base];
        const float4 f1 = *(const float4*)&Af[base + 4];
        union { unsigned u[4]; short8 s8; } cv;
        cv.u[0] = bfpair(f0.x, f0.y);
        cv.u[1] = bfpair(f0.z, f0.w);
        cv.u[2] = bfpair(f1.x, f1.y);
        cv.u[3] = bfpair(f1.z, f1.w);
        af[mt] = cv.s8;
      } else {
        af[mt] = *(const short8*)&Ab[base];
      }
    }
    short8 bfr[NT];
    #pragma unroll
    for (int nt = 0; nt < NT; ++nt)
      bfr[nt] = *(const short8*)&Wt[(size_t)(n0 + nt * 16 + ln) * K + k0 + g * 8];
    #pragma unroll
    for (int mt = 0; mt < MT; ++mt)
      #pragma unroll
      for (int nt = 0; nt < NT; ++nt)
        acc[mt][nt] = __builtin_amdgcn_mfma_f32_16x16x32_bf16(af[mt], bfr[nt], acc[mt][nt], 0, 0, 0);
  }

  #pragma unroll
  for (int mt = 0; mt < MT; ++mt)
    #pragma unroll
    for (int nt = 0; nt < NT; ++nt)
      #pragma unroll
      for (int r = 0; r < 4; ++r) {
        const int m = bm0 + mt * 16 + 4 * g + r;
        const int n = n0 + nt * 16 + ln;
        float v = acc[mt][nt][r] + bias[n];
        v = fmaxf(v, 0.f);
        if (OUT_BF16)
          ((ushort_t*)Cp)[(size_t)m * N + n] = (ushort_t)(bfpair(v, v) & 0xffffu);
        else
          ((float*)Cp)[(size_t)m * N + n] = v;
      }
}

// ---------------- fused QKV -> bf16 Q[8192x8], K[8192x8], V^T[64x8192] ----------------
__global__ __launch_bounds__(256) void qkv_k(
    const float* __restrict__ H, const float* __restrict__ Wq, const float* __restrict__ bq,
    const float* __restrict__ Wk, const float* __restrict__ bk,
    const float* __restrict__ Wv, const float* __restrict__ bv,
    ushort_t* __restrict__ Qb, ushort_t* __restrict__ Kb, ushort_t* __restrict__ VT)
{
  const int wave = threadIdx.x >> 6, lane = threadIdx.x & 63;
  const int r0b = blockIdx.x * 4;
  const int row = r0b + wave;
  __shared__ float Hs[4][64];
  __shared__ float Vs[4][64];
  Hs[wave][lane] = H[(size_t)row*64 + lane];
  __syncthreads();
  const float* h = Hs[wave];
  float va = bv[lane];
  #pragma unroll
  for (int k=0;k<64;k++) va = fmaf(h[k], Wv[k*64+lane], va);
  Vs[wave][lane] = va;
  if (lane < 16) {
    const int d = lane & 7;
    const float* Wx = (lane < 8) ? Wq : Wk;
    float a_ = (lane < 8) ? bq[d] : bk[d];
    #pragma unroll
    for (int k=0;k<64;k++) a_ = fmaf(h[k], Wx[k*8+d], a_);
    const ushort_t bits = (ushort_t)(bfpair(a_, a_) & 0xffffu);
    if (lane < 8) Qb[(size_t)row*8+d] = bits;
    else          Kb[(size_t)row*8+d] = bits;
  }
  __syncthreads();
  if (wave == 0) {
    const unsigned lo = bfpair(Vs[0][lane], Vs[1][lane]);
    const unsigned hi = bfpair(Vs[2][lane], Vs[3][lane]);
    uint2 o; o.x = lo; o.y = hi;
    *(uint2*)&VT[(size_t)lane*8192 + r0b] = o;
  }
}

// ---------------- MFMA flash attention + residual ----------------
// Block = 32 q-rows, 16 waves x 512 j's each (grid 256 -> ~4 waves/SIMD).
// Manual K-prefetch; denominator = direct f32 sum of e's (shfl-reduced once).
// Hard-coded fragment maps (HW-verified rounds 3-5).
__global__ __launch_bounds__(1024) void attn_mfma_k(
    const ushort_t* __restrict__ Qb, const ushort_t* __restrict__ Kb,
    const ushort_t* __restrict__ VT, const float* __restrict__ H3,
    const float* __restrict__ gamma, float* __restrict__ Hatt)
{
  const int wave = threadIdx.x >> 6, lane = threadIdx.x & 63;
  const int q0 = blockIdx.x * 32;
  const int m = lane & 15, g = lane >> 4;
  const f32x4 zero4 = {0.f,0.f,0.f,0.f};

  short8 qf[2] = {{0,0,0,0,0,0,0,0},{0,0,0,0,0,0,0,0}};
  if (lane < 16) {
    qf[0] = *(const short8*)&Qb[(size_t)(q0 + m) * 8];
    qf[1] = *(const short8*)&Qb[(size_t)(q0 + 16 + m) * 8];
  }

  f32x4 acc[2][4];
  #pragma unroll
  for (int qt=0;qt<2;qt++)
    #pragma unroll
    for (int dt=0;dt<4;dt++) acc[qt][dt] = zero4;
  float lsum[2] = {0.f, 0.f};

  const int j0w = wave << 9;   // 512 j per wave
  short8 kc0 = {0,0,0,0,0,0,0,0}, kc1 = {0,0,0,0,0,0,0,0};
  if (lane < 16) {
    kc0 = *(const short8*)&Kb[(size_t)(j0w + m) * 8];
    kc1 = *(const short8*)&Kb[(size_t)(j0w + 16 + m) * 8];
  }

  #pragma unroll 1
  for (int jc = 0; jc < 512; jc += 32) {
    const int jb = j0w + jc;
    // V loads for current tile (use later -> latency hidden under QK/exp)
    short8 vf[4];
    const size_t vbase = (size_t)jb + (size_t)(g << 3);
    #pragma unroll
    for (int dt=0;dt<4;dt++)
      vf[dt] = *(const short8*)&VT[(size_t)(dt*16 + m) * 8192 + vbase];
    // K prefetch for next tile
    const int jn = (jc + 32 < 512) ? (jb + 32) : j0w;
    short8 kn0 = {0,0,0,0,0,0,0,0}, kn1 = {0,0,0,0,0,0,0,0};
    if (lane < 16) {
      kn0 = *(const short8*)&Kb[(size_t)(jn + m) * 8];
      kn1 = *(const short8*)&Kb[(size_t)(jn + 16 + m) * 8];
    }
    short8 pf[2];
    #pragma unroll
    for (int qt=0;qt<2;qt++) {
      const f32x4 s0 = __builtin_amdgcn_mfma_f32_16x16x32_bf16(kc0, qf[qt], zero4, 0,0,0);
      const f32x4 s1 = __builtin_amdgcn_mfma_f32_16x16x32_bf16(kc1, qf[qt], zero4, 0,0,0);
      const float e00 = __expf(s0[0]), e01 = __expf(s0[1]), e02 = __expf(s0[2]), e03 = __expf(s0[3]);
      const float e10 = __expf(s1[0]), e11 = __expf(s1[1]), e12 = __expf(s1[2]), e13 = __expf(s1[3]);
      lsum[qt] += ((e00+e01)+(e02+e03)) + ((e10+e11)+(e12+e13));
      unsigned X01 = bfpair(e00,e01), X23 = bfpair(e02,e03);
      unsigned Y01 = bfpair(e10,e11), Y23 = bfpair(e12,e13);
      permswap32(X01, Y01); permswap16(X01, Y01);
      permswap32(X23, Y23); permswap16(X23, Y23);
      union { unsigned u[4]; short8 s; } pfu;
      pfu.u[0] = X01;   // j = 8g+0,1
      pfu.u[1] = X23;   // j = 8g+2,3
      pfu.u[2] = Y01;   // j = 8g+4,5
      pfu.u[3] = Y23;   // j = 8g+6,7
      pf[qt] = pfu.s;
    }
    #pragma unroll
    for (int dt=0;dt<4;dt++) {
      acc[0][dt] = __builtin_amdgcn_mfma_f32_16x16x32_bf16(pf[0], vf[dt], acc[0][dt], 0,0,0);
      acc[1][dt] = __builtin_amdgcn_mfma_f32_16x16x32_bf16(pf[1], vf[dt], acc[1][dt], 0,0,0);
    }
    kc0 = kn0; kc1 = kn1;
  }

  // per-query denominators: reduce lsum over the 4 g-groups
  #pragma unroll
  for (int qt=0;qt<2;qt++) {
    lsum[qt] += __shfl_xor(lsum[qt], 16, 64);
    lsum[qt] += __shfl_xor(lsum[qt], 32, 64);
  }

  __shared__ float accs[8][32][65];
  __shared__ float dss[16][32];
  if (lane < 16) {
    dss[wave][m]      = lsum[0];
    dss[wave][16 + m] = lsum[1];
  }
  if (wave >= 8) {
    const int wv = wave - 8;
    #pragma unroll
    for (int qt=0;qt<2;qt++)
      #pragma unroll
      for (int dt=0;dt<4;dt++)
        #pragma unroll
        for (int r=0;r<4;r++)
          accs[wv][qt*16 + 4*g + r][dt*16 + m] = acc[qt][dt][r];
  }
  __syncthreads();
  if (wave < 8) {
    #pragma unroll
    for (int qt=0;qt<2;qt++)
      #pragma unroll
      for (int dt=0;dt<4;dt++)
        #pragma unroll
        for (int r=0;r<4;r++)
          accs[wave][qt*16 + 4*g + r][dt*16 + m] += acc[qt][dt][r];
  }
  __syncthreads();
  const float gm = gamma[0];
  #pragma unroll
  for (int s=0;s<2;s++) {
    const int e = threadIdx.x + s * 1024;
    const int r = e >> 6, ln = e & 63;
    float denom = 0.f;
    #pragma unroll
    for (int w2=0;w2<16;w2++) denom += dss[w2][r];
    float o = 0.f;
    #pragma unroll
    for (int w2=0;w2<8;w2++) o += accs[w2][r][ln];
    const int row = q0 + r;
    Hatt[(size_t)row*64 + ln] = fmaf(gm, o/denom, H3[(size_t)row*64 + ln]);
  }
}

// ---------------- MIL attention scores ----------------
__global__ __launch_bounds__(256) void mil_scores_k(
    const float* __restrict__ Hm, const float* __restrict__ Wa1, const float* __restrict__ ba1,
    const float* __restrict__ Wa2, const float* __restrict__ ba2, float* __restrict__ scores)
{
  const int wave = threadIdx.x >> 6, lane = threadIdx.x & 63;
  const int row = blockIdx.x * 4 + wave;
  __shared__ float Hs[4][64];
  Hs[wave][lane] = Hm[(size_t)row*64 + lane];
  __syncthreads();
  const float* h = Hs[wave];
  float t = ba1[lane];
  #pragma unroll
  for (int k=0;k<64;k++) t = fmaf(h[k], Wa1[k*64+lane], t);
  t = tanhf(t);
  float part = t * Wa2[lane];
  part += __shfl_xor(part,1,64);  part += __shfl_xor(part,2,64);
  part += __shfl_xor(part,4,64);  part += __shfl_xor(part,8,64);
  part += __shfl_xor(part,16,64); part += __shfl_xor(part,32,64);
  if (lane == 0) scores[row] = part + ba2[0];
}

// ---------------- pooling stage 1 ----------------
__global__ __launch_bounds__(256) void pool1_k(
    const float* __restrict__ Hm, const float* __restrict__ scores,
    float* __restrict__ pM, float* __restrict__ pS)
{
  const int wave = threadIdx.x >> 6, lane = threadIdx.x & 63;
  const int b = blockIdx.x;
  float macc = 0.f, se = 0.f;
  for (int t=0;t<32;t++) {
    const int i = b*128 + wave*32 + t;
    const float e = __expf(scores[i]);
    se += e;
    macc = fmaf(e, Hm[(size_t)i*64 + lane], macc);
  }
  __shared__ float Ms[4][64];
  __shared__ float Ss[4];
  Ms[wave][lane] = macc;
  if (lane == 0) Ss[wave] = se;
  __syncthreads();
  if (wave == 0) {
    pM[b*64 + lane] = Ms[0][lane]+Ms[1][lane]+Ms[2][lane]+Ms[3][lane];
    if (lane == 0) pS[b] = Ss[0]+Ss[1]+Ss[2]+Ss[3];
  }
}

// ---------------- pooling stage 2 ----------------
__global__ void pool2_k(const float* __restrict__ pM, const float* __restrict__ pS,
                        const float* __restrict__ Wc, const float* __restrict__ bc,
                        float* __restrict__ out)
{
  const int lane = threadIdx.x;
  float s_ = pS[lane];
  s_ += __shfl_xor(s_,1,64);  s_ += __shfl_xor(s_,2,64);
  s_ += __shfl_xor(s_,4,64);  s_ += __shfl_xor(s_,8,64);
  s_ += __shfl_xor(s_,16,64); s_ += __shfl_xor(s_,32,64);
  float m_ = 0.f;
  for (int b=0;b<64;b++) m_ += pM[b*64+lane];
  const float Md = m_ / s_;
  out[1+lane] = Md;
  float yp = Md * Wc[lane];
  yp += __shfl_xor(yp,1,64);  yp += __shfl_xor(yp,2,64);
  yp += __shfl_xor(yp,4,64);  yp += __shfl_xor(yp,8,64);
  yp += __shfl_xor(yp,16,64); yp += __shfl_xor(yp,32,64);
  if (lane == 0) {
    float y = 1.f/(1.f + __expf(-(yp + bc[0])));
    y = fminf(fmaxf(y, 1e-5f), 1.f - 1e-5f);
    out[0] = y;
  }
}

extern "C" void kernel_launch(void* const* d_in, const int* in_sizes, int n_in,
                              void* d_out, int out_size, void* d_ws, size_t ws_size,
                              hipStream_t stream)
{
  const float* x    = (const float*)d_in[0];
  const float* W1   = (const float*)d_in[1];
  const float* b1   = (const float*)d_in[2];
  const float* W2   = (const float*)d_in[3];
  const float* b2   = (const float*)d_in[4];
  const float* W3   = (const float*)d_in[5];
  const float* b3   = (const float*)d_in[6];
  const float* Wq   = (const float*)d_in[7];
  const float* bq   = (const float*)d_in[8];
  const float* Wk   = (const float*)d_in[9];
  const float* bk   = (const float*)d_in[10];
  const float* Wv   = (const float*)d_in[11];
  const float* bv   = (const float*)d_in[12];
  const float* gam  = (const float*)d_in[13];
  const float* Wa1  = (const float*)d_in[14];
  const float* ba1  = (const float*)d_in[15];
  const float* Wa2  = (const float*)d_in[16];
  const float* ba2  = (const float*)d_in[17];
  const float* Wc   = (const float*)d_in[18];
  const float* bc   = (const float*)d_in[19];
  float* out = (float*)d_out;

  char* w = (char*)d_ws;
  float* H3 = (float*)w;        w += (size_t)8192*64*4;
  float* Ha = (float*)w;        w += (size_t)8192*64*4;
  float* sc = (float*)w;        w += 8192*4;
  float* pM = (float*)w;        w += 64*64*4;
  float* pS = (float*)w;        w += 64*4;
  ushort_t* H1b = (ushort_t*)w; w += (size_t)8192*256*2;
  ushort_t* H2b = (ushort_t*)w; w += (size_t)8192*128*2;
  ushort_t* Qb  = (ushort_t*)w; w += (size_t)8192*8*2;
  ushort_t* Kb  = (ushort_t*)w; w += (size_t)8192*8*2;
  ushort_t* VT  = (ushort_t*)w; w += (size_t)64*8192*2;
  ushort_t* W1t = (ushort_t*)w; w += (size_t)256*1024*2;
  ushort_t* W2t = (ushort_t*)w; w += (size_t)128*256*2;
  ushort_t* W3t = (ushort_t*)w; w += (size_t)64*128*2;

  transpose_bf16_k<<<dim3(256/32, 1024/32), 256, 0, stream>>>(W1, W1t, 1024, 256);
  transpose_bf16_k<<<dim3(128/32,  256/32), 256, 0, stream>>>(W2, W2t,  256, 128);
  transpose_bf16_k<<<dim3( 64/32,  128/32), 256, 0, stream>>>(W3, W3t,  128,  64);

  // MLP GEMMs: waves cover N; 16/8/4 waves per block
  gemm_mfma<1024,2,1,true ,true ><<<256, 1024, 0, stream>>>(x,   W1t, b1, H1b, 1024, 256);
  gemm_mfma< 512,1,1,false,true ><<<512,  512, 0, stream>>>(H1b, W2t, b2, H2b,  256, 128);
  gemm_mfma< 256,1,1,false,false><<<512,  256, 0, stream>>>(H2b, W3t, b3, H3,   128,  64);

  qkv_k<<<2048, 256, 0, stream>>>(H3, Wq,bq, Wk,bk, Wv,bv, Qb,Kb,VT);
  attn_mfma_k<<<256, 1024, 0, stream>>>(Qb, Kb, VT, H3, gam, Ha);
  mil_scores_k<<<2048, 256, 0, stream>>>(Ha, Wa1, ba1, Wa2, ba2, sc);
  pool1_k<<<64, 256, 0, stream>>>(Ha, sc, pM, pS);
  pool2_k<<<1, 64, 0, stream>>>(pM, pS, Wc, bc, out);
}

// Round 7
// 129.288 us; speedup vs baseline: 1.2344x; 1.2344x over previous
//
#include <hip/hip_runtime.h>
#include <math.h>

typedef unsigned short ushort_t;
typedef __attribute__((ext_vector_type(8))) short short8;
typedef __attribute__((ext_vector_type(4))) float f32x4;

// pack two f32 -> two bf16 (RNE) in one u32: D[15:0]=cvt(lo), D[31:16]=cvt(hi)
__device__ inline unsigned bfpair(float lo, float hi) {
  unsigned r;
  asm("v_cvt_pk_bf16_f32 %0, %1, %2" : "=v"(r) : "v"(lo), "v"(hi));
  return r;
}
__device__ inline ushort_t bf16of(float v) { return (ushort_t)(bfpair(v, v) & 0xffffu); }
// CDNA4 cross-half swaps (full-rate VALU):
__device__ inline void permswap32(unsigned &a, unsigned &b) {
  asm("v_permlane32_swap_b32 %0, %1" : "+v"(a), "+v"(b));
}
__device__ inline void permswap16(unsigned &a, unsigned &b) {
  asm("v_permlane16_swap_b32 %0, %1" : "+v"(a), "+v"(b));
}

// ---------------- transpose + convert: W[K][N] f32 -> Wt[N][K] bf16 ----------------
__global__ __launch_bounds__(256) void transpose_bf16_k(
    const float* __restrict__ W, ushort_t* __restrict__ Wt, int K, int N)
{
  __shared__ float Ls[32][33];
  const int t = threadIdx.x;
  const int n0 = blockIdx.x * 32, k0 = blockIdx.y * 32;
  const int tx = t & 31, tyb = t >> 5;
  #pragma unroll
  for (int s = 0; s < 4; ++s) {
    const int k = tyb + s * 8;
    Ls[k][tx] = W[(size_t)(k0 + k) * N + n0 + tx];
  }
  __syncthreads();
  #pragma unroll
  for (int s = 0; s < 2; ++s) {
    const int idx = t + 256 * s;
    const int n = idx >> 4, kk = (idx & 15) * 2;
    const unsigned pk = bfpair(Ls[kk][n], Ls[kk + 1][n]);
    *(unsigned*)&Wt[(size_t)(n0 + n) * K + k0 + kk] = pk;
  }
}

// ---------------- pack QKV weights: WqkvT[80][64] bf16 ----------------
__global__ __launch_bounds__(256) void prep_qkvw_k(
    const float* __restrict__ Wq, const float* __restrict__ Wk,
    const float* __restrict__ Wv, ushort_t* __restrict__ WqkvT)
{
  for (int e = threadIdx.x; e < 80 * 64; e += 256) {
    const int j = e >> 6, k = e & 63;
    float v;
    if (j < 8)       v = Wq[k * 8 + j];
    else if (j < 16) v = Wk[k * 8 + (j - 8)];
    else             v = Wv[k * 64 + (j - 16)];
    WqkvT[e] = bf16of(v);
  }
}

// ---------------- bf16 MFMA GEMM + bias + relu ----------------
// BM=16 rows/block, 256 thr (4 waves), wave w covers cols [w*NT*16 ...).
// Requires N == 4*NT*16. grid = M/16.
// HW-verified maps: A-frag lane(g,ln): A[m=ln][k=8g+i]; B-frag: Wt[n=..+ln][k=8g+i];
// D lane(g,ln) reg r: (row=4g+r, col=ln).
// OMODE: 0 = bf16 C0; 1 = f32 C0; 2 = f32 C0 + bf16 C1.
template<int K, int N, int NT, bool A_FP32, int OMODE>
__global__ __launch_bounds__(256) void gemm_mfma(
    const void* __restrict__ Ap, const ushort_t* __restrict__ Wt,
    const float* __restrict__ bias, void* __restrict__ C0, void* __restrict__ C1)
{
  const int wave = threadIdx.x >> 6, lane = threadIdx.x & 63;
  const int ln = lane & 15, g = lane >> 4;
  const int bm0 = blockIdx.x * 16;
  const int n0 = wave * (NT * 16);
  const f32x4 zero4 = {0.f, 0.f, 0.f, 0.f};

  f32x4 acc[NT];
  #pragma unroll
  for (int nt = 0; nt < NT; ++nt) acc[nt] = zero4;

  const float* Af = (const float*)Ap;
  const ushort_t* Ab = (const ushort_t*)Ap;

  #pragma unroll 2
  for (int k0 = 0; k0 < K; k0 += 32) {
    short8 af;
    const size_t abase = (size_t)(bm0 + ln) * K + k0 + g * 8;
    if (A_FP32) {
      const float4 f0 = *(const float4*)&Af[abase];
      const float4 f1 = *(const float4*)&Af[abase + 4];
      union { unsigned u[4]; short8 s8; } cv;
      cv.u[0] = bfpair(f0.x, f0.y);
      cv.u[1] = bfpair(f0.z, f0.w);
      cv.u[2] = bfpair(f1.x, f1.y);
      cv.u[3] = bfpair(f1.z, f1.w);
      af = cv.s8;
    } else {
      af = *(const short8*)&Ab[abase];
    }
    short8 bfr[NT];
    #pragma unroll
    for (int nt = 0; nt < NT; ++nt)
      bfr[nt] = *(const short8*)&Wt[(size_t)(n0 + nt * 16 + ln) * K + k0 + g * 8];
    #pragma unroll
    for (int nt = 0; nt < NT; ++nt)
      acc[nt] = __builtin_amdgcn_mfma_f32_16x16x32_bf16(af, bfr[nt], acc[nt], 0, 0, 0);
  }

  #pragma unroll
  for (int nt = 0; nt < NT; ++nt)
    #pragma unroll
    for (int r = 0; r < 4; ++r) {
      const int m = bm0 + 4 * g + r;
      const int n = n0 + nt * 16 + ln;
      float v = acc[nt][r] + bias[n];
      v = fmaxf(v, 0.f);
      if (OMODE == 0) {
        ((ushort_t*)C0)[(size_t)m * N + n] = bf16of(v);
      } else if (OMODE == 1) {
        ((float*)C0)[(size_t)m * N + n] = v;
      } else {
        ((float*)C0)[(size_t)m * N + n] = v;
        ((ushort_t*)C1)[(size_t)m * N + n] = bf16of(v);
      }
    }
}

// ---------------- fused QKV via MFMA: H3b[8192x64] @ WqkvT -> Qb,Kb,VT ----------------
// 1 wave per 16 instances, grid 512. NT=5 (80 output dims), K=64 (2 steps).
__global__ __launch_bounds__(64) void qkv_fused_k(
    const ushort_t* __restrict__ H3b, const ushort_t* __restrict__ WqkvT,
    const float* __restrict__ bq, const float* __restrict__ bk, const float* __restrict__ bv,
    ushort_t* __restrict__ Qb, ushort_t* __restrict__ Kb, ushort_t* __restrict__ VT)
{
  const int lane = threadIdx.x;
  const int ln = lane & 15, g = lane >> 4;
  const int q0 = blockIdx.x * 16;
  const f32x4 zero4 = {0.f, 0.f, 0.f, 0.f};
  f32x4 acc[5];
  #pragma unroll
  for (int nt = 0; nt < 5; ++nt) acc[nt] = zero4;
  #pragma unroll
  for (int k0 = 0; k0 < 64; k0 += 32) {
    const short8 af = *(const short8*)&H3b[(size_t)(q0 + ln) * 64 + k0 + g * 8];
    #pragma unroll
    for (int nt = 0; nt < 5; ++nt) {
      const short8 bfr = *(const short8*)&WqkvT[(size_t)(nt * 16 + ln) * 64 + k0 + g * 8];
      acc[nt] = __builtin_amdgcn_mfma_f32_16x16x32_bf16(af, bfr, acc[nt], 0, 0, 0);
    }
  }
  // nt=0: Q (ln<8) / K (ln>=8)
  {
    const float b0 = (ln < 8) ? bq[ln] : bk[ln - 8];
    #pragma unroll
    for (int r = 0; r < 4; ++r) {
      const int m = q0 + 4 * g + r;
      const float v = acc[0][r] + b0;
      if (ln < 8) Qb[(size_t)m * 8 + ln] = bf16of(v);
      else        Kb[(size_t)m * 8 + (ln - 8)] = bf16of(v);
    }
  }
  // nt=1..4: V^T[d][j], 4 consecutive instances per lane -> 8B store
  #pragma unroll
  for (int nt = 1; nt < 5; ++nt) {
    const int d = nt * 16 + ln - 16;
    const float b0 = bv[d];
    const float v0 = acc[nt][0] + b0, v1 = acc[nt][1] + b0;
    const float v2 = acc[nt][2] + b0, v3 = acc[nt][3] + b0;
    uint2 o; o.x = bfpair(v0, v1); o.y = bfpair(v2, v3);
    *(uint2*)&VT[(size_t)d * 8192 + q0 + 4 * g] = o;
  }
}

// ---------------- MFMA flash attention + residual (R6-verified) ----------------
// Block = 32 q-rows, 16 waves x 512 j's each (grid 256). K-prefetch.
// Also emits Ha as bf16 (Hab) for the MIL gemm.
__global__ __launch_bounds__(1024) void attn_mfma_k(
    const ushort_t* __restrict__ Qb, const ushort_t* __restrict__ Kb,
    const ushort_t* __restrict__ VT, const float* __restrict__ H3,
    const float* __restrict__ gamma, float* __restrict__ Hatt,
    ushort_t* __restrict__ Hab)
{
  const int wave = threadIdx.x >> 6, lane = threadIdx.x & 63;
  const int q0 = blockIdx.x * 32;
  const int m = lane & 15, g = lane >> 4;
  const f32x4 zero4 = {0.f,0.f,0.f,0.f};

  short8 qf[2] = {{0,0,0,0,0,0,0,0},{0,0,0,0,0,0,0,0}};
  if (lane < 16) {
    qf[0] = *(const short8*)&Qb[(size_t)(q0 + m) * 8];
    qf[1] = *(const short8*)&Qb[(size_t)(q0 + 16 + m) * 8];
  }

  f32x4 acc[2][4];
  #pragma unroll
  for (int qt=0;qt<2;qt++)
    #pragma unroll
    for (int dt=0;dt<4;dt++) acc[qt][dt] = zero4;
  float lsum[2] = {0.f, 0.f};

  const int j0w = wave << 9;   // 512 j per wave
  short8 kc0 = {0,0,0,0,0,0,0,0}, kc1 = {0,0,0,0,0,0,0,0};
  if (lane < 16) {
    kc0 = *(const short8*)&Kb[(size_t)(j0w + m) * 8];
    kc1 = *(const short8*)&Kb[(size_t)(j0w + 16 + m) * 8];
  }

  #pragma unroll 1
  for (int jc = 0; jc < 512; jc += 32) {
    const int jb = j0w + jc;
    short8 vf[4];
    const size_t vbase = (size_t)jb + (size_t)(g << 3);
    #pragma unroll
    for (int dt=0;dt<4;dt++)
      vf[dt] = *(const short8*)&VT[(size_t)(dt*16 + m) * 8192 + vbase];
    const int jn = (jc + 32 < 512) ? (jb + 32) : j0w;
    short8 kn0 = {0,0,0,0,0,0,0,0}, kn1 = {0,0,0,0,0,0,0,0};
    if (lane < 16) {
      kn0 = *(const short8*)&Kb[(size_t)(jn + m) * 8];
      kn1 = *(const short8*)&Kb[(size_t)(jn + 16 + m) * 8];
    }
    short8 pf[2];
    #pragma unroll
    for (int qt=0;qt<2;qt++) {
      const f32x4 s0 = __builtin_amdgcn_mfma_f32_16x16x32_bf16(kc0, qf[qt], zero4, 0,0,0);
      const f32x4 s1 = __builtin_amdgcn_mfma_f32_16x16x32_bf16(kc1, qf[qt], zero4, 0,0,0);
      const float e00 = __expf(s0[0]), e01 = __expf(s0[1]), e02 = __expf(s0[2]), e03 = __expf(s0[3]);
      const float e10 = __expf(s1[0]), e11 = __expf(s1[1]), e12 = __expf(s1[2]), e13 = __expf(s1[3]);
      lsum[qt] += ((e00+e01)+(e02+e03)) + ((e10+e11)+(e12+e13));
      unsigned X01 = bfpair(e00,e01), X23 = bfpair(e02,e03);
      unsigned Y01 = bfpair(e10,e11), Y23 = bfpair(e12,e13);
      permswap32(X01, Y01); permswap16(X01, Y01);
      permswap32(X23, Y23); permswap16(X23, Y23);
      union { unsigned u[4]; short8 s; } pfu;
      pfu.u[0] = X01;
      pfu.u[1] = X23;
      pfu.u[2] = Y01;
      pfu.u[3] = Y23;
      pf[qt] = pfu.s;
    }
    #pragma unroll
    for (int dt=0;dt<4;dt++) {
      acc[0][dt] = __builtin_amdgcn_mfma_f32_16x16x32_bf16(pf[0], vf[dt], acc[0][dt], 0,0,0);
      acc[1][dt] = __builtin_amdgcn_mfma_f32_16x16x32_bf16(pf[1], vf[dt], acc[1][dt], 0,0,0);
    }
    kc0 = kn0; kc1 = kn1;
  }

  #pragma unroll
  for (int qt=0;qt<2;qt++) {
    lsum[qt] += __shfl_xor(lsum[qt], 16, 64);
    lsum[qt] += __shfl_xor(lsum[qt], 32, 64);
  }

  __shared__ float accs[8][32][65];
  __shared__ float dss[16][32];
  if (lane < 16) {
    dss[wave][m]      = lsum[0];
    dss[wave][16 + m] = lsum[1];
  }
  if (wave >= 8) {
    const int wv = wave - 8;
    #pragma unroll
    for (int qt=0;qt<2;qt++)
      #pragma unroll
      for (int dt=0;dt<4;dt++)
        #pragma unroll
        for (int r=0;r<4;r++)
          accs[wv][qt*16 + 4*g + r][dt*16 + m] = acc[qt][dt][r];
  }
  __syncthreads();
  if (wave < 8) {
    #pragma unroll
    for (int qt=0;qt<2;qt++)
      #pragma unroll
      for (int dt=0;dt<4;dt++)
        #pragma unroll
        for (int r=0;r<4;r++)
          accs[wave][qt*16 + 4*g + r][dt*16 + m] += acc[qt][dt][r];
  }
  __syncthreads();
  const float gm = gamma[0];
  #pragma unroll
  for (int s=0;s<2;s++) {
    const int e = threadIdx.x + s * 1024;
    const int r = e >> 6, ln2 = e & 63;
    float denom = 0.f;
    #pragma unroll
    for (int w2=0;w2<16;w2++) denom += dss[w2][r];
    float o = 0.f;
    #pragma unroll
    for (int w2=0;w2<8;w2++) o += accs[w2][r][ln2];
    const int row = q0 + r;
    const float hv = fmaf(gm, o/denom, H3[(size_t)row*64 + ln2]);
    Hatt[(size_t)row*64 + ln2] = hv;
    Hab[(size_t)row*64 + ln2] = bf16of(hv);
  }
}

// ---------------- fused MIL scores via MFMA ----------------
// scores[m] = tanh(Ha@Wa1+ba1) @ Wa2 + ba2, 1 wave per 16 rows, grid 512.
__global__ __launch_bounds__(64) void mil_fused_k(
    const ushort_t* __restrict__ Hab, const ushort_t* __restrict__ Wa1t,
    const float* __restrict__ ba1, const float* __restrict__ Wa2,
    const float* __restrict__ ba2, float* __restrict__ scores)
{
  const int lane = threadIdx.x;
  const int ln = lane & 15, g = lane >> 4;
  const int q0 = blockIdx.x * 16;
  const f32x4 zero4 = {0.f, 0.f, 0.f, 0.f};
  f32x4 acc[4];
  #pragma unroll
  for (int nt = 0; nt < 4; ++nt) acc[nt] = zero4;
  #pragma unroll
  for (int k0 = 0; k0 < 64; k0 += 32) {
    const short8 af = *(const short8*)&Hab[(size_t)(q0 + ln) * 64 + k0 + g * 8];
    #pragma unroll
    for (int nt = 0; nt < 4; ++nt) {
      const short8 bfr = *(const short8*)&Wa1t[(size_t)(nt * 16 + ln) * 64 + k0 + g * 8];
      acc[nt] = __builtin_amdgcn_mfma_f32_16x16x32_bf16(af, bfr, acc[nt], 0, 0, 0);
    }
  }
  #pragma unroll
  for (int r = 0; r < 4; ++r) {
    float s = 0.f;
    #pragma unroll
    for (int nt = 0; nt < 4; ++nt) {
      const int n = nt * 16 + ln;
      s += tanhf(acc[nt][r] + ba1[n]) * Wa2[n];
    }
    s += __shfl_xor(s, 1, 64); s += __shfl_xor(s, 2, 64);
    s += __shfl_xor(s, 4, 64); s += __shfl_xor(s, 8, 64);
    if (ln == 0) scores[q0 + 4 * g + r] = s + ba2[0];
  }
}

// ---------------- pooling stage 1 ----------------
__global__ __launch_bounds__(256) void pool1_k(
    const float* __restrict__ Hm, const float* __restrict__ scores,
    float* __restrict__ pM, float* __restrict__ pS)
{
  const int wave = threadIdx.x >> 6, lane = threadIdx.x & 63;
  const int b = blockIdx.x;
  float macc = 0.f, se = 0.f;
  for (int t=0;t<32;t++) {
    const int i = b*128 + wave*32 + t;
    const float e = __expf(scores[i]);
    se += e;
    macc = fmaf(e, Hm[(size_t)i*64 + lane], macc);
  }
  __shared__ float Ms[4][64];
  __shared__ float Ss[4];
  Ms[wave][lane] = macc;
  if (lane == 0) Ss[wave] = se;
  __syncthreads();
  if (wave == 0) {
    pM[b*64 + lane] = Ms[0][lane]+Ms[1][lane]+Ms[2][lane]+Ms[3][lane];
    if (lane == 0) pS[b] = Ss[0]+Ss[1]+Ss[2]+Ss[3];
  }
}

// ---------------- pooling stage 2 ----------------
__global__ void pool2_k(const float* __restrict__ pM, const float* __restrict__ pS,
                        const float* __restrict__ Wc, const float* __restrict__ bc,
                        float* __restrict__ out)
{
  const int lane = threadIdx.x;
  float s_ = pS[lane];
  s_ += __shfl_xor(s_,1,64);  s_ += __shfl_xor(s_,2,64);
  s_ += __shfl_xor(s_,4,64);  s_ += __shfl_xor(s_,8,64);
  s_ += __shfl_xor(s_,16,64); s_ += __shfl_xor(s_,32,64);
  float m_ = 0.f;
  for (int b=0;b<64;b++) m_ += pM[b*64+lane];
  const float Md = m_ / s_;
  out[1+lane] = Md;
  float yp = Md * Wc[lane];
  yp += __shfl_xor(yp,1,64);  yp += __shfl_xor(yp,2,64);
  yp += __shfl_xor(yp,4,64);  yp += __shfl_xor(yp,8,64);
  yp += __shfl_xor(yp,16,64); yp += __shfl_xor(yp,32,64);
  if (lane == 0) {
    float y = 1.f/(1.f + __expf(-(yp + bc[0])));
    y = fminf(fmaxf(y, 1e-5f), 1.f - 1e-5f);
    out[0] = y;
  }
}

extern "C" void kernel_launch(void* const* d_in, const int* in_sizes, int n_in,
                              void* d_out, int out_size, void* d_ws, size_t ws_size,
                              hipStream_t stream)
{
  const float* x    = (const float*)d_in[0];
  const float* W1   = (const float*)d_in[1];
  const float* b1   = (const float*)d_in[2];
  const float* W2   = (const float*)d_in[3];
  const float* b2   = (const float*)d_in[4];
  const float* W3   = (const float*)d_in[5];
  const float* b3   = (const float*)d_in[6];
  const float* Wq   = (const float*)d_in[7];
  const float* bq   = (const float*)d_in[8];
  const float* Wk   = (const float*)d_in[9];
  const float* bk   = (const float*)d_in[10];
  const float* Wv   = (const float*)d_in[11];
  const float* bv   = (const float*)d_in[12];
  const float* gam  = (const float*)d_in[13];
  const float* Wa1  = (const float*)d_in[14];
  const float* ba1  = (const float*)d_in[15];
  const float* Wa2  = (const float*)d_in[16];
  const float* ba2  = (const float*)d_in[17];
  const float* Wc   = (const float*)d_in[18];
  const float* bc   = (const float*)d_in[19];
  float* out = (float*)d_out;

  char* w = (char*)d_ws;
  float* H3 = (float*)w;        w += (size_t)8192*64*4;
  float* Ha = (float*)w;        w += (size_t)8192*64*4;
  float* sc = (float*)w;        w += 8192*4;
  float* pM = (float*)w;        w += 64*64*4;
  float* pS = (float*)w;        w += 64*4;
  ushort_t* H1b = (ushort_t*)w; w += (size_t)8192*256*2;
  ushort_t* H2b = (ushort_t*)w; w += (size_t)8192*128*2;
  ushort_t* H3b = (ushort_t*)w; w += (size_t)8192*64*2;
  ushort_t* Hab = (ushort_t*)w; w += (size_t)8192*64*2;
  ushort_t* Qb  = (ushort_t*)w; w += (size_t)8192*8*2;
  ushort_t* Kb  = (ushort_t*)w; w += (size_t)8192*8*2;
  ushort_t* VT  = (ushort_t*)w; w += (size_t)64*8192*2;
  ushort_t* W1t = (ushort_t*)w; w += (size_t)256*1024*2;
  ushort_t* W2t = (ushort_t*)w; w += (size_t)128*256*2;
  ushort_t* W3t = (ushort_t*)w; w += (size_t)64*128*2;
  ushort_t* Wa1t= (ushort_t*)w; w += (size_t)64*64*2;
  ushort_t* Wqkv= (ushort_t*)w; w += (size_t)80*64*2;

  transpose_bf16_k<<<dim3(256/32, 1024/32), 256, 0, stream>>>(W1, W1t, 1024, 256);
  transpose_bf16_k<<<dim3(128/32,  256/32), 256, 0, stream>>>(W2, W2t,  256, 128);
  transpose_bf16_k<<<dim3( 64/32,  128/32), 256, 0, stream>>>(W3, W3t,  128,  64);
  transpose_bf16_k<<<dim3( 64/32,   64/32), 256, 0, stream>>>(Wa1, Wa1t,  64,  64);
  prep_qkvw_k<<<1, 256, 0, stream>>>(Wq, Wk, Wv, Wqkv);

  // MLP GEMMs: BM=16, 4 fat waves, grid 512 (2 blocks/CU)
  gemm_mfma<1024,256,4,true ,0><<<512, 256, 0, stream>>>(x,   W1t, b1, H1b, nullptr);
  gemm_mfma< 256,128,2,false,0><<<512, 256, 0, stream>>>(H1b, W2t, b2, H2b, nullptr);
  gemm_mfma< 128, 64,1,false,2><<<512, 256, 0, stream>>>(H2b, W3t, b3, H3,  H3b);

  qkv_fused_k<<<512, 64, 0, stream>>>(H3b, Wqkv, bq, bk, bv, Qb, Kb, VT);
  attn_mfma_k<<<256, 1024, 0, stream>>>(Qb, Kb, VT, H3, gam, Ha, Hab);
  mil_fused_k<<<512, 64, 0, stream>>>(Hab, Wa1t, ba1, Wa2, ba2, sc);
  pool1_k<<<64, 256, 0, stream>>>(Ha, sc, pM, pS);
  pool2_k<<<1, 64, 0, stream>>>(pM, pS, Wc, bc, out);
}